// Round 1
// baseline (13366.589 us; speedup 1.0000x reference)
//
#include <hip/hip_runtime.h>
#include <math.h>

// ---------------- problem constants ----------------
#define TB    2048      // T
#define CDIM  1024      // C
#define NTOKS 4096      // B*T
#define NH    16
#define NKV   4
#define DHD   64
#define FFD   4096
#define NEXP  8
#define WINSZ 1024

// ---------------- wave helpers ----------------
__device__ __forceinline__ float waveSum(float v) {
#pragma unroll
  for (int o = 32; o; o >>= 1) v += __shfl_xor(v, o, 64);
  return v;
}
__device__ __forceinline__ float waveMax(float v) {
#pragma unroll
  for (int o = 32; o; o >>= 1) v = fmaxf(v, __shfl_xor(v, o, 64));
  return v;
}

// ---------------- RMSNorm: one block per token row ----------------
__global__ __launch_bounds__(256) void rmsnorm_kernel(
    const float* __restrict__ x, const float* __restrict__ w, float* __restrict__ o) {
  int n = blockIdx.x;
  const float* xr = x + (size_t)n * CDIM;
  float s = 0.f;
  for (int i = threadIdx.x; i < CDIM; i += 256) { float v = xr[i]; s += v * v; }
  s = waveSum(s);
  __shared__ float sm[4];
  if ((threadIdx.x & 63) == 0) sm[threadIdx.x >> 6] = s;
  __syncthreads();
  float tot = sm[0] + sm[1] + sm[2] + sm[3];
  float r = rsqrtf(tot * (1.f / CDIM) + 1e-6f);
  float* orow = o + (size_t)n * CDIM;
  for (int i = threadIdx.x; i < CDIM; i += 256) orow[i] = xr[i] * r * w[i];
}

// ---------------- generic tiled f32 GEMM ----------------
// C[M,N] = A[M,K] @ B[K,N], 128x128 tile, BK=16, 256 threads, 8x8 per thread.
// Optional: row gather (rowIdx), device-dynamic M/slot base (cntPtr/ofsPtr+expertId).
// OP 0: C=acc | 1: C=silu(C)*acc | 2: C=D+alpha*acc | 3: C=acc*rowScale[row]
#define BM 128
#define BN 128
#define BK 16

template <int OP>
__global__ __launch_bounds__(256) void gemm_kernel(
    const float* __restrict__ A, const float* __restrict__ B, float* __restrict__ C,
    int M, int Nn, int Kd,
    const int* __restrict__ rowIdx, const int* __restrict__ ofsPtr,
    const int* __restrict__ cntPtr, int expertId,
    const float* __restrict__ Dres, const float* __restrict__ alphaPtr,
    const float* __restrict__ rowScale) {
  int ofs = ofsPtr ? ofsPtr[expertId] : 0;
  int Mloc = cntPtr ? cntPtr[expertId] : M;
  int rowTile = blockIdx.y * BM;
  if (rowTile >= Mloc) return;
  int colTile = blockIdx.x * BN;

  __shared__ float As[BK][BM + 4];  // transposed: As[k][m]
  __shared__ float Bs[BK][BN + 4];

  int tid = threadIdx.x;
  int tx = tid & 15, ty = tid >> 4;

  // A-tile load plan: 512 float4 slots, 2 per thread
  int s0 = tid, s1 = tid + 256;
  int ar0 = s0 >> 2, ac0 = (s0 & 3) * 4;
  int ar1 = s1 >> 2, ac1 = (s1 & 3) * 4;
  int g0 = rowTile + ar0, g1 = rowTile + ar1;
  const float* ap0 = nullptr;
  const float* ap1 = nullptr;
  if (g0 < Mloc) { int r = rowIdx ? rowIdx[ofs + g0] : (ofs + g0); ap0 = A + (size_t)r * Kd + ac0; }
  if (g1 < Mloc) { int r = rowIdx ? rowIdx[ofs + g1] : (ofs + g1); ap1 = A + (size_t)r * Kd + ac1; }
  int br0 = s0 >> 5, bc0 = (s0 & 31) * 4;
  int br1 = s1 >> 5, bc1 = (s1 & 31) * 4;
  const float* bp0 = B + (size_t)br0 * Nn + colTile + bc0;
  const float* bp1 = B + (size_t)br1 * Nn + colTile + bc1;

  float acc[8][8];
#pragma unroll
  for (int i = 0; i < 8; i++)
#pragma unroll
    for (int j = 0; j < 8; j++) acc[i][j] = 0.f;

  for (int kt = 0; kt < Kd; kt += BK) {
    float4 a0 = ap0 ? *(const float4*)(ap0 + kt) : make_float4(0.f, 0.f, 0.f, 0.f);
    float4 a1 = ap1 ? *(const float4*)(ap1 + kt) : make_float4(0.f, 0.f, 0.f, 0.f);
    float4 b0 = *(const float4*)(bp0 + (size_t)kt * Nn);
    float4 b1 = *(const float4*)(bp1 + (size_t)kt * Nn);
    __syncthreads();
    As[ac0 + 0][ar0] = a0.x; As[ac0 + 1][ar0] = a0.y; As[ac0 + 2][ar0] = a0.z; As[ac0 + 3][ar0] = a0.w;
    As[ac1 + 0][ar1] = a1.x; As[ac1 + 1][ar1] = a1.y; As[ac1 + 2][ar1] = a1.z; As[ac1 + 3][ar1] = a1.w;
    *(float4*)&Bs[br0][bc0] = b0;
    *(float4*)&Bs[br1][bc1] = b1;
    __syncthreads();
#pragma unroll
    for (int kk = 0; kk < BK; kk++) {
      float a[8], b[8];
      float4 t0 = *(const float4*)&As[kk][ty * 4];
      float4 t1 = *(const float4*)&As[kk][64 + ty * 4];
      float4 t2 = *(const float4*)&Bs[kk][tx * 4];
      float4 t3 = *(const float4*)&Bs[kk][64 + tx * 4];
      a[0] = t0.x; a[1] = t0.y; a[2] = t0.z; a[3] = t0.w;
      a[4] = t1.x; a[5] = t1.y; a[6] = t1.z; a[7] = t1.w;
      b[0] = t2.x; b[1] = t2.y; b[2] = t2.z; b[3] = t2.w;
      b[4] = t3.x; b[5] = t3.y; b[6] = t3.z; b[7] = t3.w;
#pragma unroll
      for (int i = 0; i < 8; i++)
#pragma unroll
        for (int j = 0; j < 8; j++) acc[i][j] = fmaf(a[i], b[j], acc[i][j]);
    }
  }

#pragma unroll
  for (int ii = 0; ii < 8; ii++) {
    int r = (ii < 4) ? (ty * 4 + ii) : (64 + ty * 4 + (ii - 4));
    int gr = rowTile + r;
    if (gr >= Mloc) continue;
    size_t crow = (size_t)(ofs + gr) * Nn;
#pragma unroll
    for (int jj = 0; jj < 2; jj++) {
      int c = colTile + (jj ? (64 + tx * 4) : (tx * 4));
      float* cp = C + crow + c;
      float4 vv = make_float4(acc[ii][jj * 4 + 0], acc[ii][jj * 4 + 1],
                              acc[ii][jj * 4 + 2], acc[ii][jj * 4 + 3]);
      if (OP == 0) {
        *(float4*)cp = vv;
      } else if (OP == 1) {
        float4 old = *(const float4*)cp;
        float4 ov;
        ov.x = (old.x / (1.f + __expf(-old.x))) * vv.x;
        ov.y = (old.y / (1.f + __expf(-old.y))) * vv.y;
        ov.z = (old.z / (1.f + __expf(-old.z))) * vv.z;
        ov.w = (old.w / (1.f + __expf(-old.w))) * vv.w;
        *(float4*)cp = ov;
      } else if (OP == 2) {
        float al = alphaPtr[0];
        float4 dd = *(const float4*)(Dres + crow + c);
        float4 ov = make_float4(dd.x + al * vv.x, dd.y + al * vv.y,
                                dd.z + al * vv.z, dd.w + al * vv.w);
        *(float4*)cp = ov;
      } else {
        float rs = rowScale[ofs + gr];
        float4 ov = make_float4(vv.x * rs, vv.y * rs, vv.z * rs, vv.w * rs);
        *(float4*)cp = ov;
      }
    }
  }
}

// ---------------- RoPE (in-place on q and k buffers) ----------------
__device__ __forceinline__ void rope_one(float* row, int t, int j) {
  float invf = __expf(-(float)j * (9.210340371976184f / 32.f));  // ln(10000)/32
  float ang = (float)t * invf;
  float c = cosf(ang), s = sinf(ang);
  float u0 = row[j], u1 = row[j + 32];
  row[j] = u0 * c - u1 * s;
  row[j + 32] = u1 * c + u0 * s;
}

__global__ __launch_bounds__(256) void rope_kernel(float* __restrict__ q, float* __restrict__ k) {
  int gid = blockIdx.x * 256 + threadIdx.x;
  const int QN = NTOKS * NH * 32;
  const int KN = NTOKS * NKV * 32;
  if (gid < QN) {
    int j = gid & 31;
    int h = (gid >> 5) & (NH - 1);
    int n = gid >> 9;
    rope_one(q + (size_t)n * CDIM + h * DHD, n & (TB - 1), j);
  } else if (gid < QN + KN) {
    int g2 = gid - QN;
    int j = g2 & 31;
    int g = (g2 >> 5) & (NKV - 1);
    int n = g2 >> 7;
    rope_one(k + (size_t)n * (NKV * DHD) + g * DHD, n & (TB - 1), j);
  }
}

// ---------------- attention: one wave per (b,h,q) ----------------
__global__ __launch_bounds__(256) void attn_kernel(
    const float* __restrict__ q, const float* __restrict__ k,
    const float* __restrict__ v, float* __restrict__ o) {
  int wave = threadIdx.x >> 6, lane = threadIdx.x & 63;
  int idx = blockIdx.x * 4 + wave;  // B*H*T
  int qpos = idx & (TB - 1);
  int bh = idx >> 11;
  int h = bh & (NH - 1);
  int b = bh >> 4;
  int g = h >> 2;  // NREP = 4
  int n_q = b * TB + qpos;
  float qd = q[(size_t)n_q * CDIM + h * DHD + lane];
  float m = -1e30f, l = 0.f, oacc = 0.f;
  int lo = qpos - WINSZ; if (lo < 0) lo = 0;
  for (int t0 = lo & ~63; t0 <= qpos; t0 += 64) {
    int j0 = lo - t0; if (j0 < 0) j0 = 0;
    int j1 = qpos - t0; if (j1 > 63) j1 = 63;
    float skeep = -1e30f;
    for (int j = j0; j <= j1; ++j) {
      int kp = t0 + j;
      float kv = k[(size_t)(b * TB + kp) * (NKV * DHD) + g * DHD + lane];
      float prod = waveSum(qd * kv);
      if (lane == j) skeep = prod * 0.125f;  // 1/sqrt(64)
    }
    float tmax = waveMax(skeep);
    float mnew = fmaxf(m, tmax);
    float scale = __expf(m - mnew);
    float p = __expf(skeep - mnew);  // invalid lanes underflow to 0
    float psum = waveSum(p);
    l = l * scale + psum;
    oacc *= scale;
    m = mnew;
    for (int j = j0; j <= j1; ++j) {
      float pj = __shfl(p, j, 64);
      oacc = fmaf(pj, v[(size_t)(b * TB + t0 + j) * (NKV * DHD) + g * DHD + lane], oacc);
    }
  }
  o[(size_t)n_q * CDIM + h * DHD + lane] = oacc / l;
}

// ---------------- gate: logits, top-2, aux accumulators ----------------
__global__ __launch_bounds__(256) void gate_kernel(
    const float* __restrict__ xf, const float* __restrict__ gw,
    int* __restrict__ topidx, float* __restrict__ topw,
    int* __restrict__ counts, float* __restrict__ loadAcc, float* __restrict__ zAcc) {
  int wave = threadIdx.x >> 6, lane = threadIdx.x & 63;
  int n = blockIdx.x * 4 + wave;
  const float* xr = xf + (size_t)n * CDIM;
  float acc[NEXP];
#pragma unroll
  for (int e = 0; e < NEXP; e++) acc[e] = 0.f;
  for (int i = lane; i < CDIM; i += 64) {
    float xv = xr[i];
    const float* g = gw + (size_t)i * NEXP;
#pragma unroll
    for (int e = 0; e < NEXP; e++) acc[e] = fmaf(xv, g[e], acc[e]);
  }
#pragma unroll
  for (int e = 0; e < NEXP; e++) acc[e] = waveSum(acc[e]);
  __shared__ float sprob[4][NEXP];
  __shared__ float sz[4];
  if (lane == 0) {
    int i0 = 0; float v0 = acc[0];
#pragma unroll
    for (int e = 1; e < NEXP; e++) if (acc[e] > v0) { v0 = acc[e]; i0 = e; }
    int i1 = -1; float v1 = -1e30f;
#pragma unroll
    for (int e = 0; e < NEXP; e++) if (e != i0 && acc[e] > v1) { v1 = acc[e]; i1 = e; }
    float w0 = 1.f / (1.f + __expf(v1 - v0));
    topidx[n * 2] = i0; topidx[n * 2 + 1] = i1;
    topw[n * 2] = w0;  topw[n * 2 + 1] = 1.f - w0;
    atomicAdd(&counts[i0], 1);
    atomicAdd(&counts[i1], 1);
    float se = 0.f;
#pragma unroll
    for (int e = 0; e < NEXP; e++) se += __expf(acc[e] - v0);
    float inv = 1.f / se;
#pragma unroll
    for (int e = 0; e < NEXP; e++) sprob[wave][e] = __expf(acc[e] - v0) * inv;
    float lse = v0 + logf(se);
    sz[wave] = lse * lse;
  }
  __syncthreads();
  if (threadIdx.x < NEXP) {
    float s = sprob[0][threadIdx.x] + sprob[1][threadIdx.x] +
              sprob[2][threadIdx.x] + sprob[3][threadIdx.x];
    atomicAdd(&loadAcc[threadIdx.x], s);
  } else if (threadIdx.x == NEXP) {
    atomicAdd(zAcc, sz[0] + sz[1] + sz[2] + sz[3]);
  }
}

__global__ void prefix_kernel(const int* __restrict__ counts, int* __restrict__ offsets) {
  if (threadIdx.x == 0) {
    int s = 0;
    for (int e = 0; e < NEXP; e++) { offsets[e] = s; s += counts[e]; }
  }
}

__global__ __launch_bounds__(256) void scatter_kernel(
    const int* __restrict__ topidx, const float* __restrict__ topw,
    const int* __restrict__ offsets, int* __restrict__ cursors,
    int* __restrict__ assign_token, float* __restrict__ assign_w,
    int* __restrict__ token_slot) {
  int n = blockIdx.x * 256 + threadIdx.x;
  if (n >= NTOKS) return;
  for (int kk = 0; kk < 2; kk++) {
    int e = topidx[n * 2 + kk];
    int pos = atomicAdd(&cursors[e], 1);
    int slot = offsets[e] + pos;
    assign_token[slot] = n;
    assign_w[slot] = topw[n * 2 + kk];
    token_slot[n * 2 + kk] = slot;
  }
}

// ---------------- combine: out = h + alpha_moe*(shared + routed) ----------------
__global__ __launch_bounds__(256) void combine_kernel(
    const float* __restrict__ h, const float* __restrict__ shared_o,
    const float* __restrict__ abuf, const int* __restrict__ token_slot,
    const float* __restrict__ alphaPtr, float* __restrict__ out) {
  int i4 = blockIdx.x * 256 + threadIdx.x;  // float4 index over N*C
  int n = i4 >> 8;                          // 256 float4 per row
  int cc = i4 & 255;
  float am = alphaPtr[0];
  int s0 = token_slot[n * 2], s1 = token_slot[n * 2 + 1];
  float4 hv = ((const float4*)h)[i4];
  float4 sv = ((const float4*)shared_o)[i4];
  float4 r0 = ((const float4*)abuf)[(size_t)s0 * 256 + cc];
  float4 r1 = ((const float4*)abuf)[(size_t)s1 * 256 + cc];
  float4 ov = make_float4(hv.x + am * (sv.x + r0.x + r1.x),
                          hv.y + am * (sv.y + r0.y + r1.y),
                          hv.z + am * (sv.z + r0.z + r1.z),
                          hv.w + am * (sv.w + r0.w + r1.w));
  ((float4*)out)[i4] = ov;
}

__global__ void finalize_kernel(const float* __restrict__ loadAcc,
                                const float* __restrict__ zAcc, float* __restrict__ outAux) {
  if (threadIdx.x == 0) {
    float s = 0.f;
    for (int e = 0; e < NEXP; e++) s += loadAcc[e];
    float lb = 0.f;
    for (int e = 0; e < NEXP; e++) { float f = loadAcc[e] / s; lb += f * f; }
    lb *= (float)NEXP;
    float z = zAcc[0] / (float)NTOKS;
    outAux[0] = 0.01f * lb + 0.001f * z;
  }
}

// ---------------- host orchestration ----------------
extern "C" void kernel_launch(void* const* d_in, const int* in_sizes, int n_in,
                              void* d_out, int out_size, void* d_ws, size_t ws_size,
                              hipStream_t stream) {
  const float* x   = (const float*)d_in[0];
  const float* ln1 = (const float*)d_in[1];
  const float* ln2 = (const float*)d_in[2];
  const float* wq  = (const float*)d_in[3];
  const float* wk  = (const float*)d_in[4];
  const float* wv  = (const float*)d_in[5];
  const float* wo  = (const float*)d_in[6];
  const float* sw1 = (const float*)d_in[7];
  const float* sw2 = (const float*)d_in[8];
  const float* sw3 = (const float*)d_in[9];
  const float* ew1 = (const float*)d_in[10];
  const float* ew2 = (const float*)d_in[11];
  const float* ew3 = (const float*)d_in[12];
  const float* gw  = (const float*)d_in[13];
  const float* aAttn = (const float*)d_in[14];
  const float* aMoe  = (const float*)d_in[15];

  float* ws = (float*)d_ws;
  float* xn  = ws; ws += (size_t)NTOKS * CDIM;       // xn1, later xf
  float* qb  = ws; ws += (size_t)NTOKS * CDIM;
  float* kb  = ws; ws += (size_t)NTOKS * NKV * DHD;
  float* vb  = ws; ws += (size_t)NTOKS * NKV * DHD;
  float* att = ws; ws += (size_t)NTOKS * CDIM;       // attn out, later shared_out
  float* hb  = ws; ws += (size_t)NTOKS * CDIM;
  float* mid = ws; ws += (size_t)2 * NTOKS * FFD;    // 8192 x 4096
  float* abuf = ws; ws += (size_t)2 * NTOKS * CDIM;  // 8192 x 1024
  int* ctl = (int*)ws;
  int* counts  = ctl;        // 8
  int* cursors = ctl + 8;    // 8
  float* loadAcc = (float*)(ctl + 16);  // 8
  float* zAcc = loadAcc + 8;            // 1
  int* offsets = ctl + 25;   // 8
  int* topidx = ctl + 33;            // 8192
  int* assign_token = topidx + 8192; // 8192
  int* token_slot = assign_token + 8192;  // 8192
  float* topw = (float*)(token_slot + 8192);  // 8192
  float* assign_w = topw + 8192;              // 8192

  hipMemsetAsync(counts, 0, 25 * sizeof(int), stream);  // counts+cursors+loadAcc+zAcc

  // 1) rmsnorm1
  rmsnorm_kernel<<<NTOKS, 256, 0, stream>>>(x, ln1, xn);
  // 2) QKV projections
  gemm_kernel<0><<<dim3(8, 32), 256, 0, stream>>>(xn, wq, qb, NTOKS, 1024, 1024,
      nullptr, nullptr, nullptr, 0, nullptr, nullptr, nullptr);
  gemm_kernel<0><<<dim3(2, 32), 256, 0, stream>>>(xn, wk, kb, NTOKS, 256, 1024,
      nullptr, nullptr, nullptr, 0, nullptr, nullptr, nullptr);
  gemm_kernel<0><<<dim3(2, 32), 256, 0, stream>>>(xn, wv, vb, NTOKS, 256, 1024,
      nullptr, nullptr, nullptr, 0, nullptr, nullptr, nullptr);
  // 3) RoPE
  rope_kernel<<<(NTOKS * NH * 32 + NTOKS * NKV * 32) / 256, 256, 0, stream>>>(qb, kb);
  // 4) attention
  attn_kernel<<<NTOKS * NH / 4, 256, 0, stream>>>(qb, kb, vb, att);
  // 5) wo projection + ReZero residual: h = x + alpha_attn * (att @ wo)
  gemm_kernel<2><<<dim3(8, 32), 256, 0, stream>>>(att, wo, hb, NTOKS, 1024, 1024,
      nullptr, nullptr, nullptr, 0, x, aAttn, nullptr);
  // 6) rmsnorm2 -> xf (reuse xn)
  rmsnorm_kernel<<<NTOKS, 256, 0, stream>>>(hb, ln2, xn);
  // 7) shared expert SwiGLU -> att (reused as shared_out)
  gemm_kernel<0><<<dim3(32, 32), 256, 0, stream>>>(xn, sw1, mid, NTOKS, FFD, 1024,
      nullptr, nullptr, nullptr, 0, nullptr, nullptr, nullptr);
  gemm_kernel<1><<<dim3(32, 32), 256, 0, stream>>>(xn, sw2, mid, NTOKS, FFD, 1024,
      nullptr, nullptr, nullptr, 0, nullptr, nullptr, nullptr);
  gemm_kernel<0><<<dim3(8, 32), 256, 0, stream>>>(mid, sw3, att, NTOKS, 1024, FFD,
      nullptr, nullptr, nullptr, 0, nullptr, nullptr, nullptr);
  // 8) routing
  gate_kernel<<<NTOKS / 4, 256, 0, stream>>>(xn, gw, topidx, topw, counts, loadAcc, zAcc);
  prefix_kernel<<<1, 64, 0, stream>>>(counts, offsets);
  scatter_kernel<<<NTOKS / 256, 256, 0, stream>>>(topidx, topw, offsets, cursors,
                                                  assign_token, assign_w, token_slot);
  // 9) routed experts (gathered rows, dynamic M via counts[e])
  for (int e = 0; e < NEXP; e++) {
    gemm_kernel<0><<<dim3(32, 32), 256, 0, stream>>>(
        xn, ew1 + (size_t)e * CDIM * FFD, mid, 0, FFD, CDIM,
        assign_token, offsets, counts, e, nullptr, nullptr, nullptr);
  }
  for (int e = 0; e < NEXP; e++) {
    gemm_kernel<1><<<dim3(32, 32), 256, 0, stream>>>(
        xn, ew2 + (size_t)e * CDIM * FFD, mid, 0, FFD, CDIM,
        assign_token, offsets, counts, e, nullptr, nullptr, nullptr);
  }
  for (int e = 0; e < NEXP; e++) {
    gemm_kernel<3><<<dim3(8, 32), 256, 0, stream>>>(
        mid, ew3 + (size_t)e * FFD * CDIM, abuf, 0, CDIM, FFD,
        nullptr, offsets, counts, e, nullptr, nullptr, assign_w);
  }
  // 10) combine + aux
  combine_kernel<<<NTOKS * CDIM / 4 / 256, 256, 0, stream>>>(hb, att, abuf, token_slot,
                                                             aMoe, (float*)d_out);
  finalize_kernel<<<1, 64, 0, stream>>>(loadAcc, zAcc, (float*)d_out + (size_t)NTOKS * CDIM);
}

// Round 2
// 9888.357 us; speedup vs baseline: 1.3518x; 1.3518x over previous
//
#include <hip/hip_runtime.h>
#include <math.h>

// ---------------- problem constants ----------------
#define TB    2048      // T
#define CDIM  1024      // C
#define NTOKS 4096      // B*T
#define NH    16
#define NKV   4
#define DHD   64
#define FFD   4096
#define NEXP  8
#define WINSZ 1024

// ---------------- wave helpers ----------------
__device__ __forceinline__ float waveSum(float v) {
#pragma unroll
  for (int o = 32; o; o >>= 1) v += __shfl_xor(v, o, 64);
  return v;
}

// ---------------- RMSNorm: one block per token row ----------------
__global__ __launch_bounds__(256) void rmsnorm_kernel(
    const float* __restrict__ x, const float* __restrict__ w, float* __restrict__ o) {
  int n = blockIdx.x;
  const float* xr = x + (size_t)n * CDIM;
  float s = 0.f;
  for (int i = threadIdx.x; i < CDIM; i += 256) { float v = xr[i]; s += v * v; }
  s = waveSum(s);
  __shared__ float sm[4];
  if ((threadIdx.x & 63) == 0) sm[threadIdx.x >> 6] = s;
  __syncthreads();
  float tot = sm[0] + sm[1] + sm[2] + sm[3];
  float r = rsqrtf(tot * (1.f / CDIM) + 1e-6f);
  float* orow = o + (size_t)n * CDIM;
  for (int i = threadIdx.x; i < CDIM; i += 256) orow[i] = xr[i] * r * w[i];
}

// ---------------- generic tiled f32 GEMM ----------------
#define BM 128
#define BN 128
#define BK 16

template <int OP>
__global__ __launch_bounds__(256) void gemm_kernel(
    const float* __restrict__ A, const float* __restrict__ B, float* __restrict__ C,
    int M, int Nn, int Kd,
    const int* __restrict__ rowIdx, const int* __restrict__ ofsPtr,
    const int* __restrict__ cntPtr, int expertId,
    const float* __restrict__ Dres, const float* __restrict__ alphaPtr,
    const float* __restrict__ rowScale) {
  int ofs = ofsPtr ? ofsPtr[expertId] : 0;
  int Mloc = cntPtr ? cntPtr[expertId] : M;
  int rowTile = blockIdx.y * BM;
  if (rowTile >= Mloc) return;
  int colTile = blockIdx.x * BN;

  __shared__ float As[BK][BM + 4];  // transposed: As[k][m]
  __shared__ float Bs[BK][BN + 4];

  int tid = threadIdx.x;
  int tx = tid & 15, ty = tid >> 4;

  int s0 = tid, s1 = tid + 256;
  int ar0 = s0 >> 2, ac0 = (s0 & 3) * 4;
  int ar1 = s1 >> 2, ac1 = (s1 & 3) * 4;
  int g0 = rowTile + ar0, g1 = rowTile + ar1;
  const float* ap0 = nullptr;
  const float* ap1 = nullptr;
  if (g0 < Mloc) { int r = rowIdx ? rowIdx[ofs + g0] : (ofs + g0); ap0 = A + (size_t)r * Kd + ac0; }
  if (g1 < Mloc) { int r = rowIdx ? rowIdx[ofs + g1] : (ofs + g1); ap1 = A + (size_t)r * Kd + ac1; }
  int br0 = s0 >> 5, bc0 = (s0 & 31) * 4;
  int br1 = s1 >> 5, bc1 = (s1 & 31) * 4;
  const float* bp0 = B + (size_t)br0 * Nn + colTile + bc0;
  const float* bp1 = B + (size_t)br1 * Nn + colTile + bc1;

  float acc[8][8];
#pragma unroll
  for (int i = 0; i < 8; i++)
#pragma unroll
    for (int j = 0; j < 8; j++) acc[i][j] = 0.f;

  for (int kt = 0; kt < Kd; kt += BK) {
    float4 a0 = ap0 ? *(const float4*)(ap0 + kt) : make_float4(0.f, 0.f, 0.f, 0.f);
    float4 a1 = ap1 ? *(const float4*)(ap1 + kt) : make_float4(0.f, 0.f, 0.f, 0.f);
    float4 b0 = *(const float4*)(bp0 + (size_t)kt * Nn);
    float4 b1 = *(const float4*)(bp1 + (size_t)kt * Nn);
    __syncthreads();
    As[ac0 + 0][ar0] = a0.x; As[ac0 + 1][ar0] = a0.y; As[ac0 + 2][ar0] = a0.z; As[ac0 + 3][ar0] = a0.w;
    As[ac1 + 0][ar1] = a1.x; As[ac1 + 1][ar1] = a1.y; As[ac1 + 2][ar1] = a1.z; As[ac1 + 3][ar1] = a1.w;
    *(float4*)&Bs[br0][bc0] = b0;
    *(float4*)&Bs[br1][bc1] = b1;
    __syncthreads();
#pragma unroll
    for (int kk = 0; kk < BK; kk++) {
      float a[8], b[8];
      float4 t0 = *(const float4*)&As[kk][ty * 4];
      float4 t1 = *(const float4*)&As[kk][64 + ty * 4];
      float4 t2 = *(const float4*)&Bs[kk][tx * 4];
      float4 t3 = *(const float4*)&Bs[kk][64 + tx * 4];
      a[0] = t0.x; a[1] = t0.y; a[2] = t0.z; a[3] = t0.w;
      a[4] = t1.x; a[5] = t1.y; a[6] = t1.z; a[7] = t1.w;
      b[0] = t2.x; b[1] = t2.y; b[2] = t2.z; b[3] = t2.w;
      b[4] = t3.x; b[5] = t3.y; b[6] = t3.z; b[7] = t3.w;
#pragma unroll
      for (int i = 0; i < 8; i++)
#pragma unroll
        for (int j = 0; j < 8; j++) acc[i][j] = fmaf(a[i], b[j], acc[i][j]);
    }
  }

#pragma unroll
  for (int ii = 0; ii < 8; ii++) {
    int r = (ii < 4) ? (ty * 4 + ii) : (64 + ty * 4 + (ii - 4));
    int gr = rowTile + r;
    if (gr >= Mloc) continue;
    size_t crow = (size_t)(ofs + gr) * Nn;
#pragma unroll
    for (int jj = 0; jj < 2; jj++) {
      int c = colTile + (jj ? (64 + tx * 4) : (tx * 4));
      float* cp = C + crow + c;
      float4 vv = make_float4(acc[ii][jj * 4 + 0], acc[ii][jj * 4 + 1],
                              acc[ii][jj * 4 + 2], acc[ii][jj * 4 + 3]);
      if (OP == 0) {
        *(float4*)cp = vv;
      } else if (OP == 1) {
        float4 old = *(const float4*)cp;
        float4 ov;
        ov.x = (old.x / (1.f + __expf(-old.x))) * vv.x;
        ov.y = (old.y / (1.f + __expf(-old.y))) * vv.y;
        ov.z = (old.z / (1.f + __expf(-old.z))) * vv.z;
        ov.w = (old.w / (1.f + __expf(-old.w))) * vv.w;
        *(float4*)cp = ov;
      } else if (OP == 2) {
        float al = alphaPtr[0];
        float4 dd = *(const float4*)(Dres + crow + c);
        float4 ov = make_float4(dd.x + al * vv.x, dd.y + al * vv.y,
                                dd.z + al * vv.z, dd.w + al * vv.w);
        *(float4*)cp = ov;
      } else {
        float rs = rowScale[ofs + gr];
        float4 ov = make_float4(vv.x * rs, vv.y * rs, vv.z * rs, vv.w * rs);
        *(float4*)cp = ov;
      }
    }
  }
}

// ---------------- RoPE (in-place on q and k buffers) ----------------
__device__ __forceinline__ void rope_one(float* row, int t, int j) {
  float invf = __expf(-(float)j * (9.210340371976184f / 32.f));  // ln(10000)/32
  float ang = (float)t * invf;
  float c = cosf(ang), s = sinf(ang);
  float u0 = row[j], u1 = row[j + 32];
  row[j] = u0 * c - u1 * s;
  row[j + 32] = u1 * c + u0 * s;
}

__global__ __launch_bounds__(256) void rope_kernel(float* __restrict__ q, float* __restrict__ k) {
  int gid = blockIdx.x * 256 + threadIdx.x;
  const int QN = NTOKS * NH * 32;
  const int KN = NTOKS * NKV * 32;
  if (gid < QN) {
    int j = gid & 31;
    int h = (gid >> 5) & (NH - 1);
    int n = gid >> 9;
    rope_one(q + (size_t)n * CDIM + h * DHD, n & (TB - 1), j);
  } else if (gid < QN + KN) {
    int g2 = gid - QN;
    int j = g2 & 31;
    int g = (g2 >> 5) & (NKV - 1);
    int n = g2 >> 7;
    rope_one(k + (size_t)n * (NKV * DHD) + g * DHD, n & (TB - 1), j);
  }
}

// ---------------- flash attention: one block per (b, h, 64-query tile) ----------------
// 256 threads = (ty 0..15) x (tx 0..15). Thread owns S[4q][4j] then O[4q][4d].
// LDS: Qs[64][68], KP[64][68] (K^T as [d][j], then reused as P[q][j]), Vs[64][68].
#define LSTR 68

__global__ __launch_bounds__(256) void attn_kernel(
    const float* __restrict__ q, const float* __restrict__ k,
    const float* __restrict__ v, float* __restrict__ o) {
  __shared__ float Qs[64 * LSTR];
  __shared__ float KP[64 * LSTR];
  __shared__ float Vs[64 * LSTR];

  int tid = threadIdx.x;
  int tx = tid & 15, ty = tid >> 4;
  int qt = blockIdx.x & 31;
  int h = (blockIdx.x >> 5) & (NH - 1);
  int b = blockIdx.x >> 9;
  int g = h >> 2;  // kv group (NREP=4)
  int q0 = qt * 64;

  // stage Q tile: rows q0..q0+63, cols h*64..+64
#pragma unroll
  for (int i = 0; i < 4; i++) {
    int slot = tid + 256 * i;
    int r = slot >> 4, c = (slot & 15) * 4;
    float4 qv = *(const float4*)&q[(size_t)(b * TB + q0 + r) * CDIM + h * DHD + c];
    *(float4*)&Qs[r * LSTR + c] = qv;
  }

  float O[4][4], S[4][4], m[4], l[4];
#pragma unroll
  for (int i = 0; i < 4; i++) {
    m[i] = -1e30f; l[i] = 0.f;
#pragma unroll
    for (int j = 0; j < 4; j++) O[i][j] = 0.f;
  }

  int kt0 = q0 - WINSZ; if (kt0 < 0) kt0 = 0;
  for (int kt = kt0; kt <= q0; kt += 64) {
    __syncthreads();  // prev PV done
    // stage K^T and V
#pragma unroll
    for (int i = 0; i < 4; i++) {
      int slot = tid + 256 * i;
      int r = slot >> 4, c = (slot & 15) * 4;
      const float* krow = &k[(size_t)(b * TB + kt + r) * (NKV * DHD) + g * DHD + c];
      float4 kv = *(const float4*)krow;
      KP[(c + 0) * LSTR + r] = kv.x;
      KP[(c + 1) * LSTR + r] = kv.y;
      KP[(c + 2) * LSTR + r] = kv.z;
      KP[(c + 3) * LSTR + r] = kv.w;
      const float* vrow = &v[(size_t)(b * TB + kt + r) * (NKV * DHD) + g * DHD + c];
      *(float4*)&Vs[r * LSTR + c] = *(const float4*)vrow;
    }
    __syncthreads();

    // scores: S[qi][ji] = sum_d Q[4ty+qi][d] * K[4tx+ji][d]
#pragma unroll
    for (int i = 0; i < 4; i++)
#pragma unroll
      for (int j = 0; j < 4; j++) S[i][j] = 0.f;
#pragma unroll 4
    for (int d = 0; d < 64; d++) {
      float4 k4 = *(const float4*)&KP[d * LSTR + tx * 4];
      float q0v = Qs[(ty * 4 + 0) * LSTR + d];
      float q1v = Qs[(ty * 4 + 1) * LSTR + d];
      float q2v = Qs[(ty * 4 + 2) * LSTR + d];
      float q3v = Qs[(ty * 4 + 3) * LSTR + d];
      S[0][0] = fmaf(q0v, k4.x, S[0][0]); S[0][1] = fmaf(q0v, k4.y, S[0][1]);
      S[0][2] = fmaf(q0v, k4.z, S[0][2]); S[0][3] = fmaf(q0v, k4.w, S[0][3]);
      S[1][0] = fmaf(q1v, k4.x, S[1][0]); S[1][1] = fmaf(q1v, k4.y, S[1][1]);
      S[1][2] = fmaf(q1v, k4.z, S[1][2]); S[1][3] = fmaf(q1v, k4.w, S[1][3]);
      S[2][0] = fmaf(q2v, k4.x, S[2][0]); S[2][1] = fmaf(q2v, k4.y, S[2][1]);
      S[2][2] = fmaf(q2v, k4.z, S[2][2]); S[2][3] = fmaf(q2v, k4.w, S[2][3]);
      S[3][0] = fmaf(q3v, k4.x, S[3][0]); S[3][1] = fmaf(q3v, k4.y, S[3][1]);
      S[3][2] = fmaf(q3v, k4.z, S[3][2]); S[3][3] = fmaf(q3v, k4.w, S[3][3]);
    }

    int maskDiag = (kt == q0);
    int maskEdge = (kt == q0 - WINSZ);
#pragma unroll
    for (int qi = 0; qi < 4; qi++) {
      int qg = q0 + ty * 4 + qi;
#pragma unroll
      for (int ji = 0; ji < 4; ji++) {
        int kj = kt + tx * 4 + ji;
        float s = S[qi][ji] * 0.125f;  // 1/sqrt(64)
        if (maskDiag && kj > qg) s = -1e30f;
        if (maskEdge && kj < qg - WINSZ) s = -1e30f;
        S[qi][ji] = s;
      }
      // row reduction across 16 tx lanes
      float mloc = fmaxf(fmaxf(S[qi][0], S[qi][1]), fmaxf(S[qi][2], S[qi][3]));
#pragma unroll
      for (int off = 1; off < 16; off <<= 1) mloc = fmaxf(mloc, __shfl_xor(mloc, off, 64));
      float mnew = fmaxf(m[qi], mloc);
      float sc = __expf(m[qi] - mnew);
      float psum = 0.f;
#pragma unroll
      for (int ji = 0; ji < 4; ji++) {
        float p = __expf(S[qi][ji] - mnew);
        S[qi][ji] = p;
        psum += p;
      }
#pragma unroll
      for (int off = 1; off < 16; off <<= 1) psum += __shfl_xor(psum, off, 64);
      l[qi] = l[qi] * sc + psum;
      m[qi] = mnew;
#pragma unroll
      for (int di = 0; di < 4; di++) O[qi][di] *= sc;
    }

    __syncthreads();  // done reading KP as K^T
    // write P as [q][j]
#pragma unroll
    for (int qi = 0; qi < 4; qi++)
      *(float4*)&KP[(ty * 4 + qi) * LSTR + tx * 4] =
          make_float4(S[qi][0], S[qi][1], S[qi][2], S[qi][3]);
    __syncthreads();

    // PV: O[qi][di] += sum_j P[4ty+qi][j] * V[j][4tx+di]
#pragma unroll 4
    for (int j = 0; j < 64; j++) {
      float4 v4 = *(const float4*)&Vs[j * LSTR + tx * 4];
      float p0 = KP[(ty * 4 + 0) * LSTR + j];
      float p1 = KP[(ty * 4 + 1) * LSTR + j];
      float p2 = KP[(ty * 4 + 2) * LSTR + j];
      float p3 = KP[(ty * 4 + 3) * LSTR + j];
      O[0][0] = fmaf(p0, v4.x, O[0][0]); O[0][1] = fmaf(p0, v4.y, O[0][1]);
      O[0][2] = fmaf(p0, v4.z, O[0][2]); O[0][3] = fmaf(p0, v4.w, O[0][3]);
      O[1][0] = fmaf(p1, v4.x, O[1][0]); O[1][1] = fmaf(p1, v4.y, O[1][1]);
      O[1][2] = fmaf(p1, v4.z, O[1][2]); O[1][3] = fmaf(p1, v4.w, O[1][3]);
      O[2][0] = fmaf(p2, v4.x, O[2][0]); O[2][1] = fmaf(p2, v4.y, O[2][1]);
      O[2][2] = fmaf(p2, v4.z, O[2][2]); O[2][3] = fmaf(p2, v4.w, O[2][3]);
      O[3][0] = fmaf(p3, v4.x, O[3][0]); O[3][1] = fmaf(p3, v4.y, O[3][1]);
      O[3][2] = fmaf(p3, v4.z, O[3][2]); O[3][3] = fmaf(p3, v4.w, O[3][3]);
    }
  }

  // epilogue: divide by l, store
#pragma unroll
  for (int qi = 0; qi < 4; qi++) {
    float inv = 1.f / l[qi];
    float4 ov = make_float4(O[qi][0] * inv, O[qi][1] * inv, O[qi][2] * inv, O[qi][3] * inv);
    *(float4*)&o[(size_t)(b * TB + q0 + ty * 4 + qi) * CDIM + h * DHD + tx * 4] = ov;
  }
}

// ---------------- gate: logits, top-2, aux accumulators ----------------
__global__ __launch_bounds__(256) void gate_kernel(
    const float* __restrict__ xf, const float* __restrict__ gw,
    int* __restrict__ topidx, float* __restrict__ topw,
    int* __restrict__ counts, float* __restrict__ loadAcc, float* __restrict__ zAcc) {
  int wave = threadIdx.x >> 6, lane = threadIdx.x & 63;
  int n = blockIdx.x * 4 + wave;
  const float* xr = xf + (size_t)n * CDIM;
  float acc[NEXP];
#pragma unroll
  for (int e = 0; e < NEXP; e++) acc[e] = 0.f;
  for (int i = lane; i < CDIM; i += 64) {
    float xv = xr[i];
    const float* g = gw + (size_t)i * NEXP;
#pragma unroll
    for (int e = 0; e < NEXP; e++) acc[e] = fmaf(xv, g[e], acc[e]);
  }
#pragma unroll
  for (int e = 0; e < NEXP; e++) acc[e] = waveSum(acc[e]);
  __shared__ float sprob[4][NEXP];
  __shared__ float sz[4];
  if (lane == 0) {
    int i0 = 0; float v0 = acc[0];
#pragma unroll
    for (int e = 1; e < NEXP; e++) if (acc[e] > v0) { v0 = acc[e]; i0 = e; }
    int i1 = -1; float v1 = -1e30f;
#pragma unroll
    for (int e = 0; e < NEXP; e++) if (e != i0 && acc[e] > v1) { v1 = acc[e]; i1 = e; }
    float w0 = 1.f / (1.f + __expf(v1 - v0));
    topidx[n * 2] = i0; topidx[n * 2 + 1] = i1;
    topw[n * 2] = w0;  topw[n * 2 + 1] = 1.f - w0;
    atomicAdd(&counts[i0], 1);
    atomicAdd(&counts[i1], 1);
    float se = 0.f;
#pragma unroll
    for (int e = 0; e < NEXP; e++) se += __expf(acc[e] - v0);
    float inv = 1.f / se;
#pragma unroll
    for (int e = 0; e < NEXP; e++) sprob[wave][e] = __expf(acc[e] - v0) * inv;
    float lse = v0 + logf(se);
    sz[wave] = lse * lse;
  }
  __syncthreads();
  if (threadIdx.x < NEXP) {
    float s = sprob[0][threadIdx.x] + sprob[1][threadIdx.x] +
              sprob[2][threadIdx.x] + sprob[3][threadIdx.x];
    atomicAdd(&loadAcc[threadIdx.x], s);
  } else if (threadIdx.x == NEXP) {
    atomicAdd(zAcc, sz[0] + sz[1] + sz[2] + sz[3]);
  }
}

__global__ void prefix_kernel(const int* __restrict__ counts, int* __restrict__ offsets) {
  if (threadIdx.x == 0) {
    int s = 0;
    for (int e = 0; e < NEXP; e++) { offsets[e] = s; s += counts[e]; }
  }
}

__global__ __launch_bounds__(256) void scatter_kernel(
    const int* __restrict__ topidx, const float* __restrict__ topw,
    const int* __restrict__ offsets, int* __restrict__ cursors,
    int* __restrict__ assign_token, float* __restrict__ assign_w,
    int* __restrict__ token_slot) {
  int n = blockIdx.x * 256 + threadIdx.x;
  if (n >= NTOKS) return;
  for (int kk = 0; kk < 2; kk++) {
    int e = topidx[n * 2 + kk];
    int pos = atomicAdd(&cursors[e], 1);
    int slot = offsets[e] + pos;
    assign_token[slot] = n;
    assign_w[slot] = topw[n * 2 + kk];
    token_slot[n * 2 + kk] = slot;
  }
}

// ---------------- combine: out = h + alpha_moe*(shared + routed) ----------------
__global__ __launch_bounds__(256) void combine_kernel(
    const float* __restrict__ h, const float* __restrict__ shared_o,
    const float* __restrict__ abuf, const int* __restrict__ token_slot,
    const float* __restrict__ alphaPtr, float* __restrict__ out) {
  int i4 = blockIdx.x * 256 + threadIdx.x;  // float4 index over N*C
  int n = i4 >> 8;                          // 256 float4 per row
  int cc = i4 & 255;
  float am = alphaPtr[0];
  int s0 = token_slot[n * 2], s1 = token_slot[n * 2 + 1];
  float4 hv = ((const float4*)h)[i4];
  float4 sv = ((const float4*)shared_o)[i4];
  float4 r0 = ((const float4*)abuf)[(size_t)s0 * 256 + cc];
  float4 r1 = ((const float4*)abuf)[(size_t)s1 * 256 + cc];
  float4 ov = make_float4(hv.x + am * (sv.x + r0.x + r1.x),
                          hv.y + am * (sv.y + r0.y + r1.y),
                          hv.z + am * (sv.z + r0.z + r1.z),
                          hv.w + am * (sv.w + r0.w + r1.w));
  ((float4*)out)[i4] = ov;
}

__global__ void finalize_kernel(const float* __restrict__ loadAcc,
                                const float* __restrict__ zAcc, float* __restrict__ outAux) {
  if (threadIdx.x == 0) {
    float s = 0.f;
    for (int e = 0; e < NEXP; e++) s += loadAcc[e];
    float lb = 0.f;
    for (int e = 0; e < NEXP; e++) { float f = loadAcc[e] / s; lb += f * f; }
    lb *= (float)NEXP;
    float z = zAcc[0] / (float)NTOKS;
    outAux[0] = 0.01f * lb + 0.001f * z;
  }
}

// ---------------- host orchestration ----------------
extern "C" void kernel_launch(void* const* d_in, const int* in_sizes, int n_in,
                              void* d_out, int out_size, void* d_ws, size_t ws_size,
                              hipStream_t stream) {
  const float* x   = (const float*)d_in[0];
  const float* ln1 = (const float*)d_in[1];
  const float* ln2 = (const float*)d_in[2];
  const float* wq  = (const float*)d_in[3];
  const float* wk  = (const float*)d_in[4];
  const float* wv  = (const float*)d_in[5];
  const float* wo  = (const float*)d_in[6];
  const float* sw1 = (const float*)d_in[7];
  const float* sw2 = (const float*)d_in[8];
  const float* sw3 = (const float*)d_in[9];
  const float* ew1 = (const float*)d_in[10];
  const float* ew2 = (const float*)d_in[11];
  const float* ew3 = (const float*)d_in[12];
  const float* gw  = (const float*)d_in[13];
  const float* aAttn = (const float*)d_in[14];
  const float* aMoe  = (const float*)d_in[15];

  float* ws = (float*)d_ws;
  float* xn  = ws; ws += (size_t)NTOKS * CDIM;       // xn1, later xf
  float* qb  = ws; ws += (size_t)NTOKS * CDIM;
  float* kb  = ws; ws += (size_t)NTOKS * NKV * DHD;
  float* vb  = ws; ws += (size_t)NTOKS * NKV * DHD;
  float* att = ws; ws += (size_t)NTOKS * CDIM;       // attn out, later shared_out
  float* hb  = ws; ws += (size_t)NTOKS * CDIM;
  float* mid = ws; ws += (size_t)2 * NTOKS * FFD;    // 8192 x 4096
  float* abuf = ws; ws += (size_t)2 * NTOKS * CDIM;  // 8192 x 1024
  int* ctl = (int*)ws;
  int* counts  = ctl;        // 8
  int* cursors = ctl + 8;    // 8
  float* loadAcc = (float*)(ctl + 16);  // 8
  float* zAcc = loadAcc + 8;            // 1
  int* offsets = ctl + 25;   // 8
  int* topidx = ctl + 33;            // 8192
  int* assign_token = topidx + 8192; // 8192
  int* token_slot = assign_token + 8192;  // 8192
  float* topw = (float*)(token_slot + 8192);  // 8192
  float* assign_w = topw + 8192;              // 8192

  hipMemsetAsync(counts, 0, 25 * sizeof(int), stream);  // counts+cursors+loadAcc+zAcc

  // 1) rmsnorm1
  rmsnorm_kernel<<<NTOKS, 256, 0, stream>>>(x, ln1, xn);
  // 2) QKV projections
  gemm_kernel<0><<<dim3(8, 32), 256, 0, stream>>>(xn, wq, qb, NTOKS, 1024, 1024,
      nullptr, nullptr, nullptr, 0, nullptr, nullptr, nullptr);
  gemm_kernel<0><<<dim3(2, 32), 256, 0, stream>>>(xn, wk, kb, NTOKS, 256, 1024,
      nullptr, nullptr, nullptr, 0, nullptr, nullptr, nullptr);
  gemm_kernel<0><<<dim3(2, 32), 256, 0, stream>>>(xn, wv, vb, NTOKS, 256, 1024,
      nullptr, nullptr, nullptr, 0, nullptr, nullptr, nullptr);
  // 3) RoPE
  rope_kernel<<<(NTOKS * NH * 32 + NTOKS * NKV * 32) / 256, 256, 0, stream>>>(qb, kb);
  // 4) attention (flash-style tiled)
  attn_kernel<<<1024, 256, 0, stream>>>(qb, kb, vb, att);
  // 5) wo projection + ReZero residual: h = x + alpha_attn * (att @ wo)
  gemm_kernel<2><<<dim3(8, 32), 256, 0, stream>>>(att, wo, hb, NTOKS, 1024, 1024,
      nullptr, nullptr, nullptr, 0, x, aAttn, nullptr);
  // 6) rmsnorm2 -> xf (reuse xn)
  rmsnorm_kernel<<<NTOKS, 256, 0, stream>>>(hb, ln2, xn);
  // 7) shared expert SwiGLU -> att (reused as shared_out)
  gemm_kernel<0><<<dim3(32, 32), 256, 0, stream>>>(xn, sw1, mid, NTOKS, FFD, 1024,
      nullptr, nullptr, nullptr, 0, nullptr, nullptr, nullptr);
  gemm_kernel<1><<<dim3(32, 32), 256, 0, stream>>>(xn, sw2, mid, NTOKS, FFD, 1024,
      nullptr, nullptr, nullptr, 0, nullptr, nullptr, nullptr);
  gemm_kernel<0><<<dim3(8, 32), 256, 0, stream>>>(mid, sw3, att, NTOKS, 1024, FFD,
      nullptr, nullptr, nullptr, 0, nullptr, nullptr, nullptr);
  // 8) routing
  gate_kernel<<<NTOKS / 4, 256, 0, stream>>>(xn, gw, topidx, topw, counts, loadAcc, zAcc);
  prefix_kernel<<<1, 64, 0, stream>>>(counts, offsets);
  scatter_kernel<<<NTOKS / 256, 256, 0, stream>>>(topidx, topw, offsets, cursors,
                                                  assign_token, assign_w, token_slot);
  // 9) routed experts (gathered rows, dynamic M via counts[e])
  for (int e = 0; e < NEXP; e++) {
    gemm_kernel<0><<<dim3(32, 32), 256, 0, stream>>>(
        xn, ew1 + (size_t)e * CDIM * FFD, mid, 0, FFD, CDIM,
        assign_token, offsets, counts, e, nullptr, nullptr, nullptr);
  }
  for (int e = 0; e < NEXP; e++) {
    gemm_kernel<1><<<dim3(32, 32), 256, 0, stream>>>(
        xn, ew2 + (size_t)e * CDIM * FFD, mid, 0, FFD, CDIM,
        assign_token, offsets, counts, e, nullptr, nullptr, nullptr);
  }
  for (int e = 0; e < NEXP; e++) {
    gemm_kernel<3><<<dim3(8, 32), 256, 0, stream>>>(
        mid, ew3 + (size_t)e * FFD * CDIM, abuf, 0, CDIM, FFD,
        nullptr, offsets, counts, e, nullptr, nullptr, assign_w);
  }
  // 10) combine + aux
  combine_kernel<<<NTOKS * CDIM / 4 / 256, 256, 0, stream>>>(hb, att, abuf, token_slot,
                                                             aMoe, (float*)d_out);
  finalize_kernel<<<1, 64, 0, stream>>>(loadAcc, zAcc, (float*)d_out + (size_t)NTOKS * CDIM);
}